// Round 14
// baseline (841.692 us; speedup 1.0000x reference)
//
#include <hip/hip_runtime.h>
#include <cstdint>
#include <cstddef>

typedef __attribute__((ext_vector_type(4))) float     f32x4;
typedef __attribute__((ext_vector_type(8))) __bf16    bf16x8;
typedef __attribute__((ext_vector_type(8))) short     short8;
typedef __attribute__((ext_vector_type(4))) unsigned short u16x4;
typedef unsigned short u16;

__device__ __forceinline__ float b2f(u16 u) {
  unsigned x = ((unsigned)u) << 16;
  float f;
  __builtin_memcpy(&f, &x, 4);
  return f;
}
__device__ __forceinline__ u16 f2b(float f) {
  unsigned u;
  __builtin_memcpy(&u, &f, 4);
  return (u16)((u + 0x7FFFu + ((u >> 16) & 1u)) >> 16);
}

struct GP {
  const u16*  A;
  const u16*  B;
  const float* bias;
  const void* aux;     // AMODE2: XPAD (u16)
  void*       C;
  float*      out0;    // CW8: FB (bf16, cast)
  float*      st;      // CW8: gn stats
  long long   aBS, bBS, cBS, auxBS, biasBS;
  int Ktot, Mrows, ldc;
  int cin, logW, wpad, poff;
  float scale;
};

#define GLDS16(g, l)                                                        \
  __builtin_amdgcn_global_load_lds(                                         \
      (const void __attribute__((address_space(1)))*)(g),                   \
      (void __attribute__((address_space(3)))*)(l), 16, 0, 0)

// ---------------------------------------------------------------------------
// 256x256 8-wave GEMM, split-K=2, bf16 partials (conv1).
// B-BYPASS: B (weights, L2-resident) loaded global->registers, double-
// buffered one iter ahead; LDS stages A only (4-ring of 16KB). LDS read
// traffic per half-iter drops 96KB -> 64KB (the r10-r13 structural bound).
// ---------------------------------------------------------------------------
struct G256 {
  const u16* A;
  const u16* B;
  u16* P;
  long long aBS;
  int Ktot, cin, logW, wpad, poff;
};

__global__ __launch_bounds__(512, 2) void k_gemm256(G256 gp) {
  const int tid = threadIdx.x;
  const int l = tid & 63, w = tid >> 6;
  const int lr = l & 15, lc = l >> 4;
  const int id = blockIdx.x;
  const int xcd = id & 7, slot = id >> 3;
  const int sp = xcd >> 2;
  const int u = (xcd & 3) * 32 + slot;
  const int mt = u & 15;
  const int b = u >> 4;
  const int m0 = mt << 8;
  const int wm = w >> 2, wn = w & 3;

  // A-only: 4 half-tile buffers x 8192 u16 ([256 rows][32 k])
  __shared__ __align__(16) u16 sm[4][8192];
  u16* smb = &sm[0][0];

  f32x4 acc[8][4];
#pragma unroll
  for (int i = 0; i < 8; ++i)
#pragma unroll
    for (int j = 0; j < 4; ++j) acc[i][j] = (f32x4){0.f, 0.f, 0.f, 0.f};

  const u16* Ab = gp.A + (size_t)b * gp.aBS;
  const u16* aS[2];
#pragma unroll
  for (int j = 0; j < 2; ++j) {
    const int r = j * 128 + w * 16 + (l >> 2);
    const int p = m0 + r;
    const int y = p >> gp.logW, x = p & ((1 << gp.logW) - 1);
    const int sw = ((l & 3) ^ ((r >> 1) & 3)) << 3;
    aS[j] = Ab + (size_t)((y + gp.poff) * gp.wpad + (x + gp.poff)) * gp.cin + sw;
  }
  // B per-lane register-load pointers (16x16x32 frag: col=l&15, k0=(l>>4)*8)
  const u16* bRowP[4];
#pragma unroll
  for (int ni = 0; ni < 4; ++ni)
    bRowP[ni] = gp.B + (size_t)(wn * 64 + ni * 16 + lr) * gp.Ktot + lc * 8;

  const int NH = gp.Ktot >> 6;  // half-tiles (32 K-elems) per split
  const int kt0h = sp * NH;
  int off = kt0h << 5;
  int tap = off / gp.cin;
  int kcS = off - tap * gp.cin;
  int dxS = tap % 3;
  int tapS = (tap / 3) * gp.wpad + dxS;

  auto stage = [&](int h) {
    const int hb = h & 3;
    const int kA = tapS * gp.cin + kcS;
    kcS += 32;
    if (kcS == gp.cin) {
      kcS = 0; ++dxS; ++tapS;
      if (dxS == 3) { dxS = 0; tapS += gp.wpad - 3; }
    }
    u16* base = smb + hb * 8192 + (w * 16) * 32 + l * 8;
    GLDS16(aS[0] + kA, base);
    GLDS16(aS[1] + kA, base + 4096);
  };

  // prologue: stage A h0,h1; load B(0) regs; drain; preload A regs(0)
  stage(0);
  stage(1);
  bf16x8 bv[4], bvN[4];
#pragma unroll
  for (int ni = 0; ni < 4; ++ni)
    bv[ni] = *(const bf16x8*)(bRowP[ni] + ((size_t)kt0h << 5));
  asm volatile("s_waitcnt vmcnt(0)" ::: "memory");
  __builtin_amdgcn_s_barrier();

  bf16x8 av[8];
  {
    const char* b0 = (const char*)smb;
#pragma unroll
    for (int mi = 0; mi < 8; ++mi) {
      const int row = wm * 128 + mi * 16 + lr;
      av[mi] = *(const bf16x8*)(b0 + row * 64 + ((lc ^ ((row >> 1) & 3)) << 4));
    }
  }
  asm volatile("s_waitcnt lgkmcnt(0)" ::: "memory");
  __builtin_amdgcn_s_barrier();

  for (int h = 0; h < NH; ++h) {
    const bool pf = (h + 1 < NH);
    if (h + 2 < NH) stage(h + 2);
    if (pf) {
      const size_t kB = (size_t)(kt0h + h + 1) << 5;
#pragma unroll
      for (int ni = 0; ni < 4; ++ni)
        bvN[ni] = *(const bf16x8*)(bRowP[ni] + kB);
    }

    const char* nxt = (const char*)smb + ((h + 1) & 3) * 16384;
#pragma unroll
    for (int mi = 0; mi < 8; ++mi) {
      const int row = wm * 128 + mi * 16 + lr;
      const int sw = (lc ^ ((row >> 1) & 3)) << 4;
#pragma unroll
      for (int ni = 0; ni < 4; ++ni)
        acc[mi][ni] = __builtin_amdgcn_mfma_f32_16x16x32_bf16(
            av[mi], bv[ni], acc[mi][ni], 0, 0, 0);
      if (pf) av[mi] = *(const bf16x8*)(nxt + row * 64 + sw);
    }
    if (pf) {
#pragma unroll
      for (int ni = 0; ni < 4; ++ni) bv[ni] = bvN[ni];
      asm volatile("s_waitcnt vmcnt(0)" ::: "memory");
      asm volatile("s_waitcnt lgkmcnt(0)" ::: "memory");
      __builtin_amdgcn_s_barrier();
    }
  }

  // bf16 partial store
  u16* P = gp.P + ((size_t)sp * 128 + b * 16 + mt) * 65536;
#pragma unroll
  for (int mi = 0; mi < 8; ++mi)
#pragma unroll
    for (int ni = 0; ni < 4; ++ni) {
      const int ncol = wn * 64 + ni * 16 + lr;
      const int mloc = wm * 128 + mi * 16 + lc * 4;
#pragma unroll
      for (int r = 0; r < 4; ++r)
        P[(size_t)(mloc + r) * 256 + ncol] = f2b(acc[mi][ni][r]);
    }
}

// reduce conv1 bf16 partials: relu(p0+p1+bias) -> padded NHWC bf16 H1
__global__ __launch_bounds__(256) void k_reduceH1(const u16* __restrict__ P,
                                                  const float* __restrict__ bias,
                                                  u16* __restrict__ o) {
  const int i4 = blockIdx.x * 256 + threadIdx.x;  // grid 8192 exact
  const int flat = i4 << 2;
  const int n0 = flat & 255;
  const int mloc = (flat >> 8) & 255;
  const int gm = flat >> 16;
  const u16x4 a = *(const u16x4*)(P + (size_t)gm * 65536 + mloc * 256 + n0);
  const u16x4 c = *(const u16x4*)(P + (size_t)(128 + gm) * 65536 + mloc * 256 + n0);
  const f32x4 bb = *(const f32x4*)(bias + n0);
  const int batch = gm >> 4;
  const int mg = (gm & 15) * 256 + mloc;
  const int y = mg >> 6, x = mg & 63;
  u16x4 r;
#pragma unroll
  for (int k = 0; k < 4; ++k)
    r[k] = f2b(fmaxf(b2f(a[k]) + b2f(c[k]) + bb[k], 0.f));
  *(u16x4*)(o + ((size_t)batch * 4356 + (size_t)(y + 1) * 66 + x + 1) * 256 + n0) = r;
}

// ---------------------------------------------------------------------------
// 128x256 8-wave GEMM (conv2-fused / dh1), r11 version.
// AMODE 2: first 36 K-tiles conv over gp.A (H1), then 20 tiles of 1x1 over
// gp.aux (XPAD center tap). CW 6: dh1 epilogue. CW 8: conv2 epilogue.
// ---------------------------------------------------------------------------
template <int AMODE, int CW>
__global__ __launch_bounds__(512, 2) void k_gemm8(GP gp) {
  const int tid = threadIdx.x;
  const int l = tid & 63, w = tid >> 6;
  const int b = blockIdx.z;
  const int m0 = blockIdx.x * 128;
  const int wm = w >> 2, wn = w & 3;
  const int lr = l & 15, lc = l >> 4;

  __shared__ __align__(16) u16 sm[2][24576];

  f32x4 acc[4][4];
#pragma unroll
  for (int i = 0; i < 4; ++i)
#pragma unroll
    for (int j = 0; j < 4; ++j) acc[i][j] = (f32x4){0.f, 0.f, 0.f, 0.f};

  const u16* Ab = gp.A + (size_t)b * gp.aBS;
  const u16* Bb = gp.B + (size_t)b * gp.bBS;
  const int scoff = (((tid & 7) ^ ((tid >> 3) & 7)) << 3);

  const u16* aP[2];
  const u16* aP2[2];
#pragma unroll
  for (int i = 0; i < 2; ++i) {
    const int p = m0 + i * 64 + (tid >> 3);
    const int y = p >> 6, x = p & 63;
    aP[i] = Ab + (size_t)(y * 66 + x) * gp.cin + scoff;
    if (AMODE == 2) {
      const u16* Xb = (const u16*)gp.aux + (size_t)b * gp.auxBS;
      aP2[i] = Xb + (size_t)((y + 1) * 66 + (x + 1)) * 1280 + scoff;
    }
  }
  const u16* bP[4];
#pragma unroll
  for (int i = 0; i < 4; ++i)
    bP[i] = Bb + (size_t)(i * 64 + (tid >> 3)) * gp.Ktot + scoff;

  const int NT = gp.Ktot >> 6;
  const int seg1t = (AMODE == 2) ? 36 : 0x7fffffff;
  int kcS = 0, tapS = 0, dxS = 0, nstg = 0;

  auto stage = [&](int buf) {
    const int kt = nstg++;
    const int kB = kt << 6;
    u16* sA = &sm[buf][0] + (w << 9);
    u16* sB = &sm[buf][8192] + (w << 9);
    if (AMODE == 2 && kt >= seg1t) {
      const int kA = (kt - seg1t) << 6;
      GLDS16(aP2[0] + kA, sA);
      GLDS16(aP2[1] + kA, sA + 4096);
    } else {
      const int kA = tapS * gp.cin + kcS;
      kcS += 64;
      if (kcS == gp.cin) {
        kcS = 0; ++dxS; ++tapS;
        if (dxS == 3) { dxS = 0; tapS += 63; }  // wpad(66)-3
      }
      GLDS16(aP[0] + kA, sA);
      GLDS16(aP[1] + kA, sA + 4096);
    }
    GLDS16(bP[0] + kB, sB);
    GLDS16(bP[1] + kB, sB + 4096);
    GLDS16(bP[2] + kB, sB + 8192);
    GLDS16(bP[3] + kB, sB + 12288);
  };

  stage(0);
  asm volatile("s_waitcnt vmcnt(0)" ::: "memory");
  __builtin_amdgcn_s_barrier();

  for (int t = 0; t < NT; ++t) {
    const int buf = t & 1;
    const u16* sAc = &sm[buf][0];
    const u16* sBc = &sm[buf][8192];
    if (t + 1 < NT) stage(buf ^ 1);

    bf16x8 av0[4], av1[4], bv0[4], bv1[4];
#pragma unroll
    for (int mi = 0; mi < 4; ++mi) {
      const int row = wm * 64 + mi * 16 + lr;
      av0[mi] = *(const bf16x8*)(sAc + row * 64 + (((0 + lc) ^ (row & 7)) << 3));
      av1[mi] = *(const bf16x8*)(sAc + row * 64 + (((4 + lc) ^ (row & 7)) << 3));
    }
#pragma unroll
    for (int ni = 0; ni < 4; ++ni) {
      const int row = wn * 64 + ni * 16 + lr;
      bv0[ni] = *(const bf16x8*)(sBc + row * 64 + (((0 + lc) ^ (row & 7)) << 3));
      bv1[ni] = *(const bf16x8*)(sBc + row * 64 + (((4 + lc) ^ (row & 7)) << 3));
    }
#pragma unroll
    for (int mi = 0; mi < 4; ++mi)
#pragma unroll
      for (int ni = 0; ni < 4; ++ni)
        acc[mi][ni] = __builtin_amdgcn_mfma_f32_16x16x32_bf16(
            av0[mi], bv0[ni], acc[mi][ni], 0, 0, 0);
#pragma unroll
    for (int mi = 0; mi < 4; ++mi)
#pragma unroll
      for (int ni = 0; ni < 4; ++ni)
        acc[mi][ni] = __builtin_amdgcn_mfma_f32_16x16x32_bf16(
            av1[mi], bv1[ni], acc[mi][ni], 0, 0, 0);
    asm volatile("s_waitcnt vmcnt(0)" ::: "memory");
    __builtin_amdgcn_s_barrier();
  }

  float lsum = 0.f, lsq = 0.f;
#pragma unroll
  for (int mi = 0; mi < 4; ++mi) {
#pragma unroll
    for (int ni = 0; ni < 4; ++ni) {
      const int ncol = wn * 64 + ni * 16 + lr;
      const int mbase = m0 + wm * 64 + mi * 16 + lc * 4;
      const float bv_ = gp.bias[ncol];
      if constexpr (CW == 8) {
        float* F = (float*)gp.C + (size_t)b * gp.cBS;
        u16* FB = (u16*)gp.out0 + (size_t)b * gp.cBS;
#pragma unroll
        for (int r = 0; r < 4; ++r) {
          float v = fmaxf(acc[mi][ni][r] + bv_, 0.f);
          const size_t idx = (size_t)(mbase + r) * 256 + ncol;
          F[idx] = v;
          FB[idx] = f2b(v);
          lsum += v;
          lsq += v * v;
        }
      } else {  // CW 6: dh1 -> relu(acc+bias)+mid, fp32 NCHW into d_out
        float* Cf =
            (float*)gp.C + (size_t)b * gp.cBS + (size_t)ncol * 4096 + mbase;
        const float* mid = (const float*)gp.aux + (size_t)b * gp.auxBS;
        f32x4 o;
#pragma unroll
        for (int r = 0; r < 4; ++r) {
          float v = fmaxf(acc[mi][ni][r] + bv_, 0.f);
          o[r] = v + mid[(size_t)(mbase + r) * 256 + ncol];
        }
        *(f32x4*)Cf = o;
      }
    }
  }
  if constexpr (CW == 8) {
    __syncthreads();
#pragma unroll
    for (int o = 32; o; o >>= 1) {
      lsum += __shfl_down(lsum, o);
      lsq += __shfl_down(lsq, o);
    }
    float* red = (float*)&sm[0][0];
    if (l == 0) { red[w * 2] = lsum; red[w * 2 + 1] = lsq; }
    __syncthreads();
    if (tid == 0) {
      float s = 0.f, s2 = 0.f;
#pragma unroll
      for (int k = 0; k < 8; ++k) { s += red[k * 2]; s2 += red[k * 2 + 1]; }
      atomicAdd(&gp.st[b * 2], s);
      atomicAdd(&gp.st[b * 2 + 1], s2);
    }
  }
}

// ---------------------------------------------------------------------------
// 128x128 4-wave GEMM (KV / scores / dh0).
// ---------------------------------------------------------------------------
template <int AMODE, int CW, bool RELU>
__global__ __launch_bounds__(256, 2) void k_gemm(GP gp) {
  const int tid = threadIdx.x;
  const int l = tid & 63, w = tid >> 6;
  const int b = blockIdx.z;
  const int m0 = blockIdx.x * 128, n0 = blockIdx.y * 128;
  const int wm = w >> 1, wn = w & 1;

  __shared__ __align__(16) u16 smA[128 * 64];
  __shared__ __align__(16) u16 smB[128 * 64];

  f32x4 acc[4][4];
#pragma unroll
  for (int i = 0; i < 4; ++i)
#pragma unroll
    for (int j = 0; j < 4; ++j) acc[i][j] = (f32x4){0.f, 0.f, 0.f, 0.f};

  const u16* Ab = gp.A + (size_t)b * gp.aBS;
  const u16* Bb = gp.B + (size_t)b * gp.bBS;

  const int scoff = (((l & 7) ^ (l >> 3)) << 3);

  const u16* aRow[4];
  const u16* bRow[4];
  u16* ldsA[4];
  u16* ldsB[4];
#pragma unroll
  for (int i = 0; i < 4; ++i) {
    const int r = w * 32 + i * 8 + (l >> 3);
    bRow[i] = Bb + (size_t)(n0 + r) * gp.Ktot + scoff;
    const int p = m0 + r;
    if (AMODE == 0) {
      const int pc = p < gp.Mrows ? p : gp.Mrows - 1;
      aRow[i] = Ab + (size_t)pc * gp.Ktot + scoff;
    } else {
      const int y = p >> gp.logW, x = p & ((1 << gp.logW) - 1);
      const int icoord = (y + gp.poff) * gp.wpad + (x + gp.poff);
      aRow[i] = Ab + (size_t)icoord * gp.cin + scoff;
    }
    ldsA[i] = smA + (w * 32 + i * 8) * 64;
    ldsB[i] = smB + (w * 32 + i * 8) * 64;
  }

  const int ktiles = gp.Ktot >> 6;
  int tap_off = 0, dx = 0, kc = 0;

  for (int kt = 0; kt < ktiles; ++kt) {
    int koffA;
    if (AMODE == 0)
      koffA = kt << 6;
    else
      koffA = tap_off * gp.cin + kc;
    const int koffB = kt << 6;
#pragma unroll
    for (int i = 0; i < 4; ++i) GLDS16(aRow[i] + koffA, ldsA[i]);
#pragma unroll
    for (int i = 0; i < 4; ++i) GLDS16(bRow[i] + koffB, ldsB[i]);

    if (AMODE == 1) {
      kc += 64;
      if (kc == gp.cin) {
        kc = 0;
        ++dx;
        ++tap_off;
        if (dx == 3) { dx = 0; tap_off += gp.wpad - 3; }
      }
    }

    __syncthreads();
#pragma unroll
    for (int ks = 0; ks < 2; ++ks) {
      bf16x8 av[4], bv[4];
      const int cc = (ks << 2) + (l >> 4);
#pragma unroll
      for (int mi = 0; mi < 4; ++mi) {
        const int row = wm * 64 + mi * 16 + (l & 15);
        av[mi] = *(const bf16x8*)((const char*)smA + (row << 7) +
                                  ((cc ^ (row & 7)) << 4));
      }
#pragma unroll
      for (int ni = 0; ni < 4; ++ni) {
        const int row = wn * 64 + ni * 16 + (l & 15);
        bv[ni] = *(const bf16x8*)((const char*)smB + (row << 7) +
                                  ((cc ^ (row & 7)) << 4));
      }
#pragma unroll
      for (int mi = 0; mi < 4; ++mi)
#pragma unroll
        for (int ni = 0; ni < 4; ++ni)
          acc[mi][ni] = __builtin_amdgcn_mfma_f32_16x16x32_bf16(
              av[mi], bv[ni], acc[mi][ni], 0, 0, 0);
    }
    __syncthreads();
  }

#pragma unroll
  for (int mi = 0; mi < 4; ++mi) {
#pragma unroll
    for (int ni = 0; ni < 4; ++ni) {
      const int ncol = n0 + wn * 64 + ni * 16 + (l & 15);
      const int mbase = m0 + wm * 64 + mi * 16 + ((l >> 4) << 2);
      const float bv_ =
          gp.bias ? gp.bias[(size_t)b * gp.biasBS + ncol] : 0.f;

      if constexpr (CW == 7) {
        u16* base = (u16*)gp.C;
        if (ncol < 256) {
#pragma unroll
          for (int r = 0; r < 4; ++r)
            base[(size_t)b * 1048576 + (size_t)(mbase + r) * 256 + ncol] =
                f2b(acc[mi][ni][r] + bv_);
        } else {
          u16x4 pk;
#pragma unroll
          for (int r = 0; r < 4; ++r) pk[r] = f2b(acc[mi][ni][r] + bv_);
          *(u16x4*)(base + 8388608 + (size_t)b * 1048576 +
                    (size_t)(ncol - 256) * 4096 + mbase) = pk;
        }
      } else {
#pragma unroll
        for (int reg = 0; reg < 4; ++reg) {
          const int mrow = mbase + reg;
          if (mrow >= gp.Mrows) continue;
          float v = acc[mi][ni][reg] * gp.scale + bv_;
          if (RELU) v = v > 0.f ? v : 0.f;
          if constexpr (CW == 0) {
            ((u16*)gp.C)[(size_t)b * gp.cBS + (size_t)mrow * gp.ldc + ncol] =
                f2b(v);
          } else if constexpr (CW == 5) {
            ((float*)gp.C)[(size_t)b * gp.cBS + (size_t)mrow * 256 + ncol] = v;
          }
        }
      }
    }
  }
}

// ---------------------------------------------------------------------------
// attnV split-K=4: SCORES[1025][4096] x V^T[256][4096], K-chunk 1024/block.
// grid (9, 2, 32): z = b*4 + sp. fp32 partials -> PAV[z][1025][256].
// ---------------------------------------------------------------------------
__global__ __launch_bounds__(256, 2) void k_attnv(const u16* __restrict__ S,
                                                  const u16* __restrict__ Vv,
                                                  float* __restrict__ PAV) {
  const int tid = threadIdx.x;
  const int l = tid & 63, w = tid >> 6;
  const int b = blockIdx.z >> 2, sp = blockIdx.z & 3;
  const int m0 = blockIdx.x * 128, n0 = blockIdx.y * 128;
  const int wm = w >> 1, wn = w & 1;

  __shared__ __align__(16) u16 smA[128 * 64];
  __shared__ __align__(16) u16 smB[128 * 64];

  f32x4 acc[4][4];
#pragma unroll
  for (int i = 0; i < 4; ++i)
#pragma unroll
    for (int j = 0; j < 4; ++j) acc[i][j] = (f32x4){0.f, 0.f, 0.f, 0.f};

  const u16* Ab = S + (size_t)b * 4198400 + sp * 1024;
  const u16* Bb = Vv + (size_t)b * 1048576 + sp * 1024;
  const int scoff = (((l & 7) ^ (l >> 3)) << 3);

  const u16* aRow[4];
  const u16* bRow[4];
  u16* ldsA[4];
  u16* ldsB[4];
#pragma unroll
  for (int i = 0; i < 4; ++i) {
    const int r = w * 32 + i * 8 + (l >> 3);
    bRow[i] = Bb + (size_t)(n0 + r) * 4096 + scoff;
    const int p = m0 + r;
    const int pc = p < 1025 ? p : 1024;
    aRow[i] = Ab + (size_t)pc * 4096 + scoff;
    ldsA[i] = smA + (w * 32 + i * 8) * 64;
    ldsB[i] = smB + (w * 32 + i * 8) * 64;
  }

  for (int kt = 0; kt < 16; ++kt) {
    const int koff = kt << 6;
#pragma unroll
    for (int i = 0; i < 4; ++i) GLDS16(aRow[i] + koff, ldsA[i]);
#pragma unroll
    for (int i = 0; i < 4; ++i) GLDS16(bRow[i] + koff, ldsB[i]);

    __syncthreads();
#pragma unroll
    for (int ks = 0; ks < 2; ++ks) {
      bf16x8 av[4], bv[4];
      const int cc = (ks << 2) + (l >> 4);
#pragma unroll
      for (int mi = 0; mi < 4; ++mi) {
        const int row = wm * 64 + mi * 16 + (l & 15);
        av[mi] = *(const bf16x8*)((const char*)smA + (row << 7) +
                                  ((cc ^ (row & 7)) << 4));
      }
#pragma unroll
      for (int ni = 0; ni < 4; ++ni) {
        const int row = wn * 64 + ni * 16 + (l & 15);
        bv[ni] = *(const bf16x8*)((const char*)smB + (row << 7) +
                                  ((cc ^ (row & 7)) << 4));
      }
#pragma unroll
      for (int mi = 0; mi < 4; ++mi)
#pragma unroll
        for (int ni = 0; ni < 4; ++ni)
          acc[mi][ni] = __builtin_amdgcn_mfma_f32_16x16x32_bf16(
              av[mi], bv[ni], acc[mi][ni], 0, 0, 0);
    }
    __syncthreads();
  }

  float* P = PAV + (size_t)blockIdx.z * 262400;
#pragma unroll
  for (int mi = 0; mi < 4; ++mi) {
#pragma unroll
    for (int ni = 0; ni < 4; ++ni) {
      const int ncol = n0 + wn * 64 + ni * 16 + (l & 15);
      const int mbase = m0 + wm * 64 + mi * 16 + ((l >> 4) << 2);
#pragma unroll
      for (int r = 0; r < 4; ++r) {
        const int mrow = mbase + r;
        if (mrow >= 1025) continue;
        P[(size_t)mrow * 256 + ncol] = acc[mi][ni][r];
      }
    }
  }
}

// reduce attnV partials: sum 4 splits; row0 -> out0 fp32; rows 1..1024 ->
// OCP 34x34-pad bf16. grid (257, 8).
__global__ __launch_bounds__(256) void k_reduceAttn(const float* __restrict__ PAV,
                                                    float* __restrict__ out0,
                                                    u16* __restrict__ OCP) {
  const int b = blockIdx.y;
  const int i4 = blockIdx.x * 256 + threadIdx.x;
  if (i4 >= 65600) return;  // 1025*256/4
  const int flat = i4 << 2;
  const int row = flat >> 8;
  const int col = flat & 255;
  const float* base = PAV + (size_t)(b * 4) * 262400 + (size_t)row * 256 + col;
  f32x4 s = *(const f32x4*)base;
  s += *(const f32x4*)(base + 262400);
  s += *(const f32x4*)(base + 524800);
  s += *(const f32x4*)(base + 787200);
  if (row == 0) {
    *(f32x4*)(out0 + (size_t)b * 256 + col) = s;
  } else {
    const int p = row - 1, y = p >> 5, x = p & 31;
    u16x4 r;
#pragma unroll
    for (int k = 0; k < 4; ++k) r[k] = f2b(s[k]);
    *(u16x4*)(OCP + ((size_t)b * 1156 + (size_t)(y + 1) * 34 + x + 1) * 256 +
              col) = r;
  }
}

// --------------------------- prep / misc kernels ---------------------------

__global__ __launch_bounds__(256) void k_prep_x(const float* __restrict__ x,
                                                u16* __restrict__ o) {
  __shared__ float t[32][65];
  const int b = blockIdx.z, c0 = blockIdx.y << 5, y = blockIdx.x;
  const float* src = x + ((size_t)b * 1280 + c0) * 4096 + (size_t)y * 64;
#pragma unroll
  for (int i = 0; i < 8; ++i) {
    const int idx = threadIdx.x + (i << 8);
    const int c = idx >> 6, xx = idx & 63;
    t[c][xx] = src[(size_t)c * 4096 + xx];
  }
  __syncthreads();
  u16* dst = o + ((size_t)b * 4356 + (size_t)(y + 1) * 66 + 1) * 1280 + c0;
  const int xx = threadIdx.x >> 2;
  const int cq = (threadIdx.x & 3) << 3;
  short8 pk;
#pragma unroll
  for (int j = 0; j < 8; ++j) pk[j] = (short)f2b(t[cq + j][xx]);
  *(short8*)(dst + (size_t)xx * 1280 + cq) = pk;
}

__device__ __forceinline__ void zb1(u16* p, int P, int C, int idx) {
  const int per_img = (4 * P - 4) * C;
  const int b = idx / per_img;
  const int r = idx % per_img;
  const int pix = r / C, c = r % C;
  int y, x;
  const int Pm = P - 1;
  if (pix < P) { y = 0; x = pix; }
  else if (pix < 2 * P) { y = Pm; x = pix - P; }
  else if (pix < 3 * P - 2) { y = pix - 2 * P + 1; x = 0; }
  else { y = pix - (3 * P - 2) + 1; x = Pm; }
  p[((size_t)b * P * P + (size_t)y * P + x) * C + c] = 0;
}

__global__ __launch_bounds__(256) void k_zero_borders(u16* XPAD, u16* H1,
                                                      u16* G2, u16* OCP) {
  const int nx = 8 * 260 * 1280;
  const int nh = 8 * 260 * 256;
  const int no = 8 * 132 * 256;
  const int total = nx + 2 * nh + no;
  for (int i = blockIdx.x * 256 + threadIdx.x; i < total;
       i += gridDim.x * 256) {
    if (i < nx) zb1(XPAD, 66, 1280, i);
    else if (i < nx + nh) zb1(H1, 66, 256, i - nx);
    else if (i < nx + 2 * nh) zb1(G2, 66, 256, i - nx - nh);
    else zb1(OCP, 34, 256, i - nx - 2 * nh);
  }
}

__global__ __launch_bounds__(256) void k_prep_all(
    const float* __restrict__ w1, const float* __restrict__ w2,
    const float* __restrict__ wsc, const float* __restrict__ wd0,
    const float* __restrict__ wd1, const float* __restrict__ b2,
    const float* __restrict__ bsc, const float* __restrict__ q,
    u16* __restrict__ W1R, u16* __restrict__ WCAT2, u16* __restrict__ WD0R,
    u16* __restrict__ WD1R, float* __restrict__ BB2, u16* __restrict__ QB) {
  const int N1 = 2949120, N2 = 917504, N3 = 589824, N4 = 589824,
            N5 = 2099200, N6 = 256;
  const int T = N1 + N2 + N3 + N4 + N5 + N6;
  for (int i = blockIdx.x * 256 + threadIdx.x; i < T; i += gridDim.x * 256) {
    if (i < N1) {
      const int ci = i % 1280, r = i / 1280, t = r % 9, co = r / 9;
      W1R[i] = f2b(w1[((size_t)co * 1280 + ci) * 9 + t]);
    } else if (i < N1 + N2) {
      const int k = i - N1;
      const int co = k / 3584, kk = k % 3584;
      float v;
      if (kk < 2304) {
        const int tap = kk / 256, ci = kk % 256;
        v = w2[((size_t)co * 256 + ci) * 9 + tap];
      } else {
        v = wsc[(size_t)co * 1280 + (kk - 2304)];
      }
      WCAT2[k] = f2b(v);
    } else if (i < N1 + N2 + N3) {
      const int k = i - N1 - N2;
      const int ci = k % 256, r = k / 256, t = r % 9, co = r / 9;
      WD0R[k] = f2b(wd0[((size_t)co * 256 + ci) * 9 + t]);
    } else if (i < N1 + N2 + N3 + N4) {
      const int k = i - N1 - N2 - N3;
      const int ci = k % 256, r = k / 256, t = r % 9, co = r / 9;
      WD1R[k] = f2b(wd1[((size_t)co * 256 + ci) * 9 + t]);
    } else if (i < N1 + N2 + N3 + N4 + N5) {
      const int k = i - N1 - N2 - N3 - N4;
      QB[k] = f2b(q[k] * 0.0625f);
    } else {
      const int k = i - N1 - N2 - N3 - N4 - N5;
      BB2[k] = b2[k] + bsc[k];
    }
  }
}

__global__ __launch_bounds__(256) void k_foldkv(
    const float* __restrict__ wk, const float* __restrict__ wv,
    const float* __restrict__ bk, const float* __restrict__ bv,
    const float* __restrict__ g, const float* __restrict__ lnb,
    const float* __restrict__ st, u16* __restrict__ WKVB,
    float* __restrict__ BKVB) {
  const int idx = blockIdx.x * 256 + threadIdx.x;
  const int b = idx >> 9, j = idx & 511;
  const float mu = st[b * 2] * (1.f / 1048576.f);
  const float var = st[b * 2 + 1] * (1.f / 1048576.f) - mu * mu;
  const float rs = rsqrtf(var + 1e-6f);
  const float* wrow = (j < 256) ? wk + (size_t)j * 256 : wv + (size_t)(j - 256) * 256;
  float acc = (j < 256) ? bk[j] : bv[j - 256];
  u16* orow = WKVB + ((size_t)b * 512 + j) * 256;
  for (int c = 0; c < 256; ++c) {
    const float wv_ = wrow[c];
    orow[c] = f2b(wv_ * g[c] * rs);
    acc += wv_ * (lnb[c] - mu * rs * g[c]);
  }
  BKVB[b * 512 + j] = acc;
}

template <bool PAD>
__global__ __launch_bounds__(256) void k_gn_norm(const float* __restrict__ x,
                                                 const float* __restrict__ st,
                                                 const float* __restrict__ g,
                                                 const float* __restrict__ bb,
                                                 u16* __restrict__ o) {
  const int b = blockIdx.y;
  const float mu = st[b * 2] * (1.f / 1048576.f);
  const float var = st[b * 2 + 1] * (1.f / 1048576.f) - mu * mu;
  const float rs = rsqrtf(var + 1e-6f);
  const int i4 = blockIdx.x * 256 + threadIdx.x;
  const f32x4 v = ((const f32x4*)(x + (size_t)b * 1048576))[i4];
  const int flat = i4 << 2;
  const int c = flat & 255;
  const int p = flat >> 8;
  const f32x4 gv = *(const f32x4*)(g + c);
  const f32x4 bv = *(const f32x4*)(bb + c);
  u16x4 r;
#pragma unroll
  for (int k = 0; k < 4; ++k) r[k] = f2b((v[k] - mu) * rs * gv[k] + bv[k]);
  size_t oidx;
  if (PAD) {
    const int y = p >> 6, xx = p & 63;
    oidx = ((size_t)b * 4356 + (size_t)(y + 1) * 66 + xx + 1) * 256 + c;
  } else {
    oidx = ((size_t)b * 4096 + p) * 256 + c;
  }
  *(u16x4*)(o + oidx) = r;
}

__global__ __launch_bounds__(256) void k_softmax(u16* __restrict__ s) {
  const size_t row = blockIdx.x;
  u16* p = s + row * 4096;
  const int t = threadIdx.x;
  const short8 r0 = ((const short8*)p)[t];
  const short8 r1 = ((const short8*)p)[t + 256];
  float v[16];
#pragma unroll
  for (int i = 0; i < 8; ++i) {
    v[i] = b2f((u16)r0[i]);
    v[8 + i] = b2f((u16)r1[i]);
  }
  float m = v[0];
#pragma unroll
  for (int i = 1; i < 16; ++i) m = fmaxf(m, v[i]);
#pragma unroll
  for (int o = 32; o; o >>= 1) m = fmaxf(m, __shfl_xor(m, o));
  __shared__ float lm[4], lsum[4];
  const int w = t >> 6;
  if ((t & 63) == 0) lm[w] = m;
  __syncthreads();
  m = fmaxf(fmaxf(lm[0], lm[1]), fmaxf(lm[2], lm[3]));
  float sum = 0.f;
#pragma unroll
  for (int i = 0; i < 16; ++i) {
    v[i] = __expf(v[i] - m);
    sum += v[i];
  }
#pragma unroll
  for (int o = 32; o; o >>= 1) sum += __shfl_xor(sum, o);
  if ((t & 63) == 0) lsum[w] = sum;
  __syncthreads();
  sum = lsum[0] + lsum[1] + lsum[2] + lsum[3];
  const float inv = 1.f / sum;
  short8 o0, o1;
#pragma unroll
  for (int i = 0; i < 8; ++i) {
    o0[i] = (short)f2b(v[i] * inv);
    o1[i] = (short)f2b(v[8 + i] * inv);
  }
  ((short8*)p)[t] = o0;
  ((short8*)p)[t + 256] = o1;
}

// bilinear 32->64 + add F -> mid, fused gn2 stats. grid (64, 8).
__global__ __launch_bounds__(256) void k_resize_add(const float* __restrict__ d0,
                                                    const float* __restrict__ F,
                                                    float* __restrict__ mid,
                                                    float* __restrict__ st) {
  const int b = blockIdx.y;
  const float* db = d0 + (size_t)b * 262144;
  const float* Fb = F + (size_t)b * 1048576;
  float* mb = mid + (size_t)b * 1048576;
  float ls = 0.f, lq = 0.f;
  for (int i4 = blockIdx.x * 256 + threadIdx.x; i4 < 262144;
       i4 += 64 * 256) {
    const int flat = i4 << 2;
    const int c = flat & 255;
    const int p = flat >> 8;
    const int y = p >> 6, x = p & 63;
    const float fy = y * (31.f / 63.f);
    const int y0 = (int)fy;
    const float wy = fy - y0;
    const int y1 = y0 + 1 > 31 ? 31 : y0 + 1;
    const float fx = x * (31.f / 63.f);
    const int x0 = (int)fx;
    const float wx = fx - x0;
    const int x1 = x0 + 1 > 31 ? 31 : x0 + 1;
    const f32x4 a = *(const f32x4*)(db + ((size_t)(y0 * 32 + x0) << 8) + c);
    const f32x4 bq = *(const f32x4*)(db + ((size_t)(y0 * 32 + x1) << 8) + c);
    const f32x4 cq = *(const f32x4*)(db + ((size_t)(y1 * 32 + x0) << 8) + c);
    const f32x4 dq = *(const f32x4*)(db + ((size_t)(y1 * 32 + x1) << 8) + c);
    f32x4 r = (a * (1.f - wx) + bq * wx) * (1.f - wy) +
              (cq * (1.f - wx) + dq * wx) * wy;
    r += *(const f32x4*)(Fb + flat);
    *(f32x4*)(mb + flat) = r;
    ls += r[0] + r[1] + r[2] + r[3];
    lq += r[0] * r[0] + r[1] * r[1] + r[2] * r[2] + r[3] * r[3];
  }
#pragma unroll
  for (int o = 32; o; o >>= 1) {
    ls += __shfl_down(ls, o);
    lq += __shfl_down(lq, o);
  }
  __shared__ float red[8];
  const int w = threadIdx.x >> 6;
  if ((threadIdx.x & 63) == 0) { red[w * 2] = ls; red[w * 2 + 1] = lq; }
  __syncthreads();
  if (threadIdx.x == 0) {
    atomicAdd(&st[16 + b * 2], red[0] + red[2] + red[4] + red[6]);
    atomicAdd(&st[16 + b * 2 + 1], red[1] + red[3] + red[5] + red[7]);
  }
}

// ---------------------------------------------------------------------------

extern "C" void kernel_launch(void* const* d_in, const int* in_sizes, int n_in,
                              void* d_out, int out_size, void* d_ws,
                              size_t ws_size, hipStream_t stream) {
  (void)in_sizes; (void)n_in; (void)out_size;

  const float* q   = (const float*)d_in[0];
  const float* xdc = (const float*)d_in[1];
  const float* w1  = (const float*)d_in[2];
  const float* b1  = (const float*)d_in[3];
  const float* w2  = (const float*)d_in[4];
  const float* b2  = (const float*)d_in[5];
  const float* wsc = (const float*)d_in[6];
  const float* bsc = (const float*)d_in[7];
  const float* lng = (const float*)d_in[8];
  const float* lnb = (const float*)d_in[9];
  const float* wk  = (const float*)d_in[10];
  const float* bk  = (const float*)d_in[11];
  const float* wv  = (const float*)d_in[12];
  const float* bv  = (const float*)d_in[13];
  const float* wd0 = (const float*)d_in[14];
  const float* bd0 = (const float*)d_in[15];
  const float* wd1 = (const float*)d_in[16];
  const float* bd1 = (const float*)d_in[17];

  char* ws = (char*)d_ws;
  size_t cur = 0;
  auto alloc = [&](size_t sz) {
    char* p = ws + cur;
    cur += sz;
    return p;
  };
  u16* XPAD  = (u16*)alloc(89194496);   // 8*66*66*1280; SCORES alias later
  u16* W1R   = (u16*)alloc(5898240);
  u16* WCAT2 = (u16*)alloc(1835008);    // 256 x 3584 (w2 taps || wsc)
  u16* WD0R  = (u16*)alloc(1179648);
  u16* WD1R  = (u16*)alloc(1179648);
  u16* WKVB  = (u16*)alloc(2097152);    // 8 x 512 x 256 folded kv weights
  float* BKVB = (float*)alloc(16384);   // 8 x 512
  float* BB2 = (float*)alloc(1024);     // b2 + bsc
  u16* H1    = (u16*)alloc(17842176);   // conv1 out, padded NHWC bf16
  float* F   = (float*)alloc(33554432); // feat_diff NHWC fp32
  u16* FB    = (u16*)alloc(16777216);   // bf16(F), unnormalized
  u16* KT    = (u16*)alloc(16777216);   // key [pixel][256]
  u16* V     = (u16*)alloc(16777216);   // value [f][pixel] (MUST follow KT)
  u16* QB    = (u16*)alloc(4198400);    // query bf16 [1025][256], pre-scaled
  u16* OCP   = (u16*)alloc(4734976);    // attn spatial out, 34x34 pad NHWC
  float* D0O = (float*)alloc(8388608);  // dh0 out NHWC fp32 (32x32)
  float* MID = (float*)alloc(33554432); // out_p mid NHWC fp32
  u16* G2    = (u16*)alloc(17842176);   // gn2 out, padded NHWC bf16
  float* ST  = (float*)alloc(256);      // [0:16) gn1, [16:32) gn2
  u16* SCORES = XPAD;                   // XPAD dead after conv2 (seg2 read)
  u16* PART = (u16*)F;                  // 33.5MB bf16 conv1 partials over F
  float* PAV  = D0O;                    // 33.6MB attnV partials over D0O+MID
  (void)V;

  if (ws_size < cur) return;

  float* out0 = (float*)d_out;
  float* out1 = (float*)d_out + 2048;

  hipMemsetAsync(ST, 0, 256, stream);
  k_zero_borders<<<2048, 256, 0, stream>>>(XPAD, H1, G2, OCP);
  k_prep_x<<<dim3(64, 40, 8), 256, 0, stream>>>(xdc, XPAD);
  k_prep_all<<<4096, 256, 0, stream>>>(w1, w2, wsc, wd0, wd1, b2, bsc, q, W1R,
                                       WCAT2, WD0R, WD1R, BB2, QB);

  // conv1 3x3 via B-bypass 256x256 split-K kernel -> bf16 partials -> H1
  {
    G256 g{};
    g.A = XPAD; g.B = W1R; g.P = PART;
    g.aBS = 5575680; g.Ktot = 11520;
    g.cin = 1280; g.logW = 6; g.wpad = 66; g.poff = 0;
    k_gemm256<<<256, 512, 0, stream>>>(g);
    k_reduceH1<<<8192, 256, 0, stream>>>(PART, b1, H1);
  }
  // conv2 3x3 (K=2304 over H1) + fused shortcut (K=1280 over XPAD center):
  {
    GP g{};
    g.A = H1; g.B = WCAT2; g.bias = BB2; g.aux = XPAD; g.C = F;
    g.out0 = (float*)FB; g.st = ST;
    g.aBS = 1115136; g.bBS = 0; g.cBS = 1048576; g.auxBS = 5575680;
    g.Ktot = 3584; g.Mrows = 4096; g.ldc = 256;
    g.cin = 256; g.logW = 6; g.wpad = 66; g.poff = 0; g.scale = 1.f;
    k_gemm8<2, 8><<<dim3(32, 1, 8), 512, 0, stream>>>(g);
  }
  // fold gn1 into kv weights (per batch)
  k_foldkv<<<16, 256, 0, stream>>>(wk, wv, bk, bv, lng, lnb, ST, WKVB, BKVB);
  // fused key+value 1x1: FB x WKVB(+BKVB) -> KT, V
  {
    GP g{};
    g.A = FB; g.B = WKVB; g.bias = BKVB; g.C = KT;
    g.aBS = 1048576; g.bBS = 131072; g.cBS = 0; g.biasBS = 512;
    g.Ktot = 256; g.Mrows = 4096; g.ldc = 256; g.scale = 1.f;
    k_gemm<0, 7, false><<<dim3(32, 4, 8), 256, 0, stream>>>(g);
  }
  // scores: QB (pre-scaled) x KT^T -> SCORES bf16 [1025][4096]
  {
    GP g{};
    g.A = QB; g.B = KT; g.bias = nullptr; g.C = SCORES;
    g.aBS = 262400; g.bBS = 1048576; g.cBS = 4198400;
    g.Ktot = 256; g.Mrows = 1025; g.ldc = 4096; g.scale = 1.f;
    k_gemm<0, 0, false><<<dim3(9, 32, 8), 256, 0, stream>>>(g);
  }
  k_softmax<<<8200, 256, 0, stream>>>(SCORES);
  // attn out: split-K=4 -> partials -> reduce (out0 + OCP)
  k_attnv<<<dim3(9, 2, 32), 256, 0, stream>>>(SCORES, V, PAV);
  k_reduceAttn<<<dim3(257, 8), 256, 0, stream>>>(PAV, out0, OCP);
  // dh0 3x3 @32x32 (overwrites dead PAV region at D0O)
  {
    GP g{};
    g.A = OCP; g.B = WD0R; g.bias = bd0; g.C = D0O;
    g.aBS = 295936; g.bBS = 0; g.cBS = 262144; g.biasBS = 0;
    g.Ktot = 2304; g.Mrows = 1024; g.ldc = 256;
    g.cin = 256; g.logW = 5; g.wpad = 34; g.poff = 0; g.scale = 1.f;
    k_gemm<1, 5, true><<<dim3(8, 2, 8), 256, 0, stream>>>(g);
  }
  // bilinear upsample + add F -> MID, + gn2 stats (1024 atomics total)
  k_resize_add<<<dim3(64, 8), 256, 0, stream>>>(D0O, F, MID, ST);
  k_gn_norm<true><<<dim3(1024, 8), 256, 0, stream>>>(MID, ST + 16, lng, lnb, G2);
  // dh1 3x3: G2 x WD1R, relu(acc+bias)+MID -> out1 (NCHW fp32)
  {
    GP g{};
    g.A = G2; g.B = WD1R; g.bias = bd1; g.C = out1; g.aux = MID;
    g.aBS = 1115136; g.bBS = 0; g.cBS = 1048576; g.auxBS = 1048576;
    g.Ktot = 2304; g.Mrows = 4096; g.ldc = 256;
    g.cin = 256; g.logW = 6; g.wpad = 66; g.poff = 0; g.scale = 1.f;
    k_gemm8<1, 6><<<dim3(32, 1, 8), 512, 0, stream>>>(g);
  }
}

// Round 15
// 659.279 us; speedup vs baseline: 1.2767x; 1.2767x over previous
//
#include <hip/hip_runtime.h>
#include <cstdint>
#include <cstddef>

typedef __attribute__((ext_vector_type(4))) float     f32x4;
typedef __attribute__((ext_vector_type(8))) __bf16    bf16x8;
typedef __attribute__((ext_vector_type(8))) short     short8;
typedef __attribute__((ext_vector_type(4))) unsigned short u16x4;
typedef unsigned short u16;

__device__ __forceinline__ float b2f(u16 u) {
  unsigned x = ((unsigned)u) << 16;
  float f;
  __builtin_memcpy(&f, &x, 4);
  return f;
}
__device__ __forceinline__ u16 f2b(float f) {
  unsigned u;
  __builtin_memcpy(&u, &f, 4);
  return (u16)((u + 0x7FFFu + ((u >> 16) & 1u)) >> 16);
}

struct GP {
  const u16*  A;
  const u16*  B;
  const float* bias;
  const void* aux;     // AMODE2: XPAD (u16)
  void*       C;
  float*      out0;    // CW8: FB (bf16, cast)
  float*      st;      // CW8: gn stats
  long long   aBS, bBS, cBS, auxBS, biasBS;
  int Ktot, Mrows, ldc;
  int cin, logW, wpad, poff;
  float scale;
};

#define GLDS16(g, l)                                                        \
  __builtin_amdgcn_global_load_lds(                                         \
      (const void __attribute__((address_space(1)))*)(g),                   \
      (void __attribute__((address_space(3)))*)(l), 16, 0, 0)

// ---------------------------------------------------------------------------
// 256x256 8-wave GEMM, split-K=2, BF16 partials (conv1). Reg-prefetch
// (r10 schedule; LDS-BW bound at ~94% -- frozen; r14 B-bypass reverted).
// ---------------------------------------------------------------------------
struct G256 {
  const u16* A;
  const u16* B;
  u16* P;
  long long aBS;
  int Ktot, cin, logW, wpad, poff;
};

__global__ __launch_bounds__(512, 2) void k_gemm256(G256 gp) {
  const int tid = threadIdx.x;
  const int l = tid & 63, w = tid >> 6;
  const int lr = l & 15, lc = l >> 4;
  const int id = blockIdx.x;
  const int xcd = id & 7, slot = id >> 3;
  const int sp = xcd >> 2;
  const int u = (xcd & 3) * 32 + slot;
  const int mt = u & 15;
  const int b = u >> 4;
  const int m0 = mt << 8;
  const int wm = w >> 2, wn = w & 3;

  __shared__ __align__(16) u16 sm[4][16384];
  u16* smb = &sm[0][0];

  f32x4 acc[8][4];
#pragma unroll
  for (int i = 0; i < 8; ++i)
#pragma unroll
    for (int j = 0; j < 4; ++j) acc[i][j] = (f32x4){0.f, 0.f, 0.f, 0.f};

  const u16* Ab = gp.A + (size_t)b * gp.aBS;
  const u16* aS[2];
  const u16* bS[2];
#pragma unroll
  for (int j = 0; j < 2; ++j) {
    const int r = j * 128 + w * 16 + (l >> 2);
    const int p = m0 + r;
    const int y = p >> gp.logW, x = p & ((1 << gp.logW) - 1);
    const int sw = ((l & 3) ^ ((r >> 1) & 3)) << 3;
    aS[j] = Ab + (size_t)((y + gp.poff) * gp.wpad + (x + gp.poff)) * gp.cin + sw;
    bS[j] = gp.B + (size_t)r * gp.Ktot + sw;
  }

  const int NH = gp.Ktot >> 6;
  const int kt0h = sp * NH;
  int off = kt0h << 5;
  int tap = off / gp.cin;
  int kcS = off - tap * gp.cin;
  int dxS = tap % 3;
  int tapS = (tap / 3) * gp.wpad + dxS;
  int hgS = kt0h;

  auto stage = [&](int h) {
    const int hb = h & 3;
    const int kB = hgS << 5;
    const int kA = tapS * gp.cin + kcS;
    kcS += 32;
    if (kcS == gp.cin) {
      kcS = 0; ++dxS; ++tapS;
      if (dxS == 3) { dxS = 0; tapS += gp.wpad - 3; }
    }
    ++hgS;
    u16* base = smb + hb * 16384 + (w * 16) * 32 + l * 8;
    GLDS16(aS[0] + kA, base);
    GLDS16(aS[1] + kA, base + 4096);
    GLDS16(bS[0] + kB, base + 8192);
    GLDS16(bS[1] + kB, base + 12288);
  };

  stage(0);
  stage(1);
  stage(2);
  asm volatile("s_waitcnt vmcnt(8)" ::: "memory");
  __builtin_amdgcn_s_barrier();

  bf16x8 av[8], bv[4];
  {
    const char* b0 = (const char*)smb;
#pragma unroll
    for (int mi = 0; mi < 8; ++mi) {
      const int row = wm * 128 + mi * 16 + lr;
      av[mi] = *(const bf16x8*)(b0 + row * 64 + ((lc ^ ((row >> 1) & 3)) << 4));
    }
#pragma unroll
    for (int ni = 0; ni < 4; ++ni) {
      const int row = wn * 64 + ni * 16 + lr;
      bv[ni] = *(const bf16x8*)(b0 + 16384 + row * 64 +
                                ((lc ^ ((row >> 1) & 3)) << 4));
    }
  }

  for (int h = 0; h < NH; ++h) {
    if (h + 3 < NH) stage(h + 3);
    const int rem = NH - 1 - h;
    if (rem > 0) {
      if (rem > 2)
        asm volatile("s_waitcnt vmcnt(8)" ::: "memory");
      else if (rem == 2)
        asm volatile("s_waitcnt vmcnt(4)" ::: "memory");
      else
        asm volatile("s_waitcnt vmcnt(0)" ::: "memory");
      asm volatile("s_waitcnt lgkmcnt(0)" ::: "memory");
      __builtin_amdgcn_s_barrier();
    }

    const bool pf = (h + 1 < NH);
    const char* nxt = (const char*)smb + ((h + 1) & 3) * 32768;

#pragma unroll
    for (int mi = 0; mi < 8; ++mi) {
      const int row = wm * 128 + mi * 16 + lr;
      const int sw = (lc ^ ((row >> 1) & 3)) << 4;
#pragma unroll
      for (int ni = 0; ni < 4; ++ni)
        acc[mi][ni] = __builtin_amdgcn_mfma_f32_16x16x32_bf16(
            av[mi], bv[ni], acc[mi][ni], 0, 0, 0);
      if (pf) av[mi] = *(const bf16x8*)(nxt + row * 64 + sw);
    }
    if (pf) {
#pragma unroll
      for (int ni = 0; ni < 4; ++ni) {
        const int row = wn * 64 + ni * 16 + lr;
        bv[ni] = *(const bf16x8*)(nxt + 16384 + row * 64 +
                                  ((lc ^ ((row >> 1) & 3)) << 4));
      }
    }
  }

  // bf16 partial store
  u16* P = gp.P + ((size_t)sp * 128 + b * 16 + mt) * 65536;
#pragma unroll
  for (int mi = 0; mi < 8; ++mi)
#pragma unroll
    for (int ni = 0; ni < 4; ++ni) {
      const int ncol = wn * 64 + ni * 16 + lr;
      const int mloc = wm * 128 + mi * 16 + lc * 4;
#pragma unroll
      for (int r = 0; r < 4; ++r)
        P[(size_t)(mloc + r) * 256 + ncol] = f2b(acc[mi][ni][r]);
    }
}

// reduce conv1 bf16 partials: relu(p0+p1+bias) -> padded NHWC bf16 H1
__global__ __launch_bounds__(256) void k_reduceH1(const u16* __restrict__ P,
                                                  const float* __restrict__ bias,
                                                  u16* __restrict__ o) {
  const int i4 = blockIdx.x * 256 + threadIdx.x;  // grid 8192 exact
  const int flat = i4 << 2;
  const int n0 = flat & 255;
  const int mloc = (flat >> 8) & 255;
  const int gm = flat >> 16;
  const u16x4 a = *(const u16x4*)(P + (size_t)gm * 65536 + mloc * 256 + n0);
  const u16x4 c = *(const u16x4*)(P + (size_t)(128 + gm) * 65536 + mloc * 256 + n0);
  const f32x4 bb = *(const f32x4*)(bias + n0);
  const int batch = gm >> 4;
  const int mg = (gm & 15) * 256 + mloc;
  const int y = mg >> 6, x = mg & 63;
  u16x4 r;
#pragma unroll
  for (int k = 0; k < 4; ++k)
    r[k] = f2b(fmaxf(b2f(a[k]) + b2f(c[k]) + bb[k], 0.f));
  *(u16x4*)(o + ((size_t)batch * 4356 + (size_t)(y + 1) * 66 + x + 1) * 256 + n0) = r;
}

// ---------------------------------------------------------------------------
// 128x256 8-wave GEMM (conv2-fused / dh1), r11 version.
// AMODE 2: first 36 K-tiles conv over gp.A (H1), then 20 tiles of 1x1 over
// gp.aux (XPAD center tap). CW 6: dh1 epilogue. CW 8: conv2 epilogue.
// ---------------------------------------------------------------------------
template <int AMODE, int CW>
__global__ __launch_bounds__(512, 2) void k_gemm8(GP gp) {
  const int tid = threadIdx.x;
  const int l = tid & 63, w = tid >> 6;
  const int b = blockIdx.z;
  const int m0 = blockIdx.x * 128;
  const int wm = w >> 2, wn = w & 3;
  const int lr = l & 15, lc = l >> 4;

  __shared__ __align__(16) u16 sm[2][24576];

  f32x4 acc[4][4];
#pragma unroll
  for (int i = 0; i < 4; ++i)
#pragma unroll
    for (int j = 0; j < 4; ++j) acc[i][j] = (f32x4){0.f, 0.f, 0.f, 0.f};

  const u16* Ab = gp.A + (size_t)b * gp.aBS;
  const u16* Bb = gp.B + (size_t)b * gp.bBS;
  const int scoff = (((tid & 7) ^ ((tid >> 3) & 7)) << 3);

  const u16* aP[2];
  const u16* aP2[2];
#pragma unroll
  for (int i = 0; i < 2; ++i) {
    const int p = m0 + i * 64 + (tid >> 3);
    const int y = p >> 6, x = p & 63;
    aP[i] = Ab + (size_t)(y * 66 + x) * gp.cin + scoff;
    if (AMODE == 2) {
      const u16* Xb = (const u16*)gp.aux + (size_t)b * gp.auxBS;
      aP2[i] = Xb + (size_t)((y + 1) * 66 + (x + 1)) * 1280 + scoff;
    }
  }
  const u16* bP[4];
#pragma unroll
  for (int i = 0; i < 4; ++i)
    bP[i] = Bb + (size_t)(i * 64 + (tid >> 3)) * gp.Ktot + scoff;

  const int NT = gp.Ktot >> 6;
  const int seg1t = (AMODE == 2) ? 36 : 0x7fffffff;
  int kcS = 0, tapS = 0, dxS = 0, nstg = 0;

  auto stage = [&](int buf) {
    const int kt = nstg++;
    const int kB = kt << 6;
    u16* sA = &sm[buf][0] + (w << 9);
    u16* sB = &sm[buf][8192] + (w << 9);
    if (AMODE == 2 && kt >= seg1t) {
      const int kA = (kt - seg1t) << 6;
      GLDS16(aP2[0] + kA, sA);
      GLDS16(aP2[1] + kA, sA + 4096);
    } else {
      const int kA = tapS * gp.cin + kcS;
      kcS += 64;
      if (kcS == gp.cin) {
        kcS = 0; ++dxS; ++tapS;
        if (dxS == 3) { dxS = 0; tapS += 63; }  // wpad(66)-3
      }
      GLDS16(aP[0] + kA, sA);
      GLDS16(aP[1] + kA, sA + 4096);
    }
    GLDS16(bP[0] + kB, sB);
    GLDS16(bP[1] + kB, sB + 4096);
    GLDS16(bP[2] + kB, sB + 8192);
    GLDS16(bP[3] + kB, sB + 12288);
  };

  stage(0);
  asm volatile("s_waitcnt vmcnt(0)" ::: "memory");
  __builtin_amdgcn_s_barrier();

  for (int t = 0; t < NT; ++t) {
    const int buf = t & 1;
    const u16* sAc = &sm[buf][0];
    const u16* sBc = &sm[buf][8192];
    if (t + 1 < NT) stage(buf ^ 1);

    bf16x8 av0[4], av1[4], bv0[4], bv1[4];
#pragma unroll
    for (int mi = 0; mi < 4; ++mi) {
      const int row = wm * 64 + mi * 16 + lr;
      av0[mi] = *(const bf16x8*)(sAc + row * 64 + (((0 + lc) ^ (row & 7)) << 3));
      av1[mi] = *(const bf16x8*)(sAc + row * 64 + (((4 + lc) ^ (row & 7)) << 3));
    }
#pragma unroll
    for (int ni = 0; ni < 4; ++ni) {
      const int row = wn * 64 + ni * 16 + lr;
      bv0[ni] = *(const bf16x8*)(sBc + row * 64 + (((0 + lc) ^ (row & 7)) << 3));
      bv1[ni] = *(const bf16x8*)(sBc + row * 64 + (((4 + lc) ^ (row & 7)) << 3));
    }
#pragma unroll
    for (int mi = 0; mi < 4; ++mi)
#pragma unroll
      for (int ni = 0; ni < 4; ++ni)
        acc[mi][ni] = __builtin_amdgcn_mfma_f32_16x16x32_bf16(
            av0[mi], bv0[ni], acc[mi][ni], 0, 0, 0);
#pragma unroll
    for (int mi = 0; mi < 4; ++mi)
#pragma unroll
      for (int ni = 0; ni < 4; ++ni)
        acc[mi][ni] = __builtin_amdgcn_mfma_f32_16x16x32_bf16(
            av1[mi], bv1[ni], acc[mi][ni], 0, 0, 0);
    asm volatile("s_waitcnt vmcnt(0)" ::: "memory");
    __builtin_amdgcn_s_barrier();
  }

  float lsum = 0.f, lsq = 0.f;
#pragma unroll
  for (int mi = 0; mi < 4; ++mi) {
#pragma unroll
    for (int ni = 0; ni < 4; ++ni) {
      const int ncol = wn * 64 + ni * 16 + lr;
      const int mbase = m0 + wm * 64 + mi * 16 + lc * 4;
      const float bv_ = gp.bias[ncol];
      if constexpr (CW == 8) {
        float* F = (float*)gp.C + (size_t)b * gp.cBS;
        u16* FB = (u16*)gp.out0 + (size_t)b * gp.cBS;
#pragma unroll
        for (int r = 0; r < 4; ++r) {
          float v = fmaxf(acc[mi][ni][r] + bv_, 0.f);
          const size_t idx = (size_t)(mbase + r) * 256 + ncol;
          F[idx] = v;
          FB[idx] = f2b(v);
          lsum += v;
          lsq += v * v;
        }
      } else {  // CW 6: dh1 -> relu(acc+bias)+mid, fp32 NCHW into d_out
        float* Cf =
            (float*)gp.C + (size_t)b * gp.cBS + (size_t)ncol * 4096 + mbase;
        const float* mid = (const float*)gp.aux + (size_t)b * gp.auxBS;
        f32x4 o;
#pragma unroll
        for (int r = 0; r < 4; ++r) {
          float v = fmaxf(acc[mi][ni][r] + bv_, 0.f);
          o[r] = v + mid[(size_t)(mbase + r) * 256 + ncol];
        }
        *(f32x4*)Cf = o;
      }
    }
  }
  if constexpr (CW == 8) {
    __syncthreads();
#pragma unroll
    for (int o = 32; o; o >>= 1) {
      lsum += __shfl_down(lsum, o);
      lsq += __shfl_down(lsq, o);
    }
    float* red = (float*)&sm[0][0];
    if (l == 0) { red[w * 2] = lsum; red[w * 2 + 1] = lsq; }
    __syncthreads();
    if (tid == 0) {
      float s = 0.f, s2 = 0.f;
#pragma unroll
      for (int k = 0; k < 8; ++k) { s += red[k * 2]; s2 += red[k * 2 + 1]; }
      atomicAdd(&gp.st[b * 2], s);
      atomicAdd(&gp.st[b * 2 + 1], s2);
    }
  }
}

// ---------------------------------------------------------------------------
// 128x128 4-wave GEMM (KV / scores / dh0).
// ---------------------------------------------------------------------------
template <int AMODE, int CW, bool RELU>
__global__ __launch_bounds__(256, 2) void k_gemm(GP gp) {
  const int tid = threadIdx.x;
  const int l = tid & 63, w = tid >> 6;
  const int b = blockIdx.z;
  const int m0 = blockIdx.x * 128, n0 = blockIdx.y * 128;
  const int wm = w >> 1, wn = w & 1;

  __shared__ __align__(16) u16 smA[128 * 64];
  __shared__ __align__(16) u16 smB[128 * 64];

  f32x4 acc[4][4];
#pragma unroll
  for (int i = 0; i < 4; ++i)
#pragma unroll
    for (int j = 0; j < 4; ++j) acc[i][j] = (f32x4){0.f, 0.f, 0.f, 0.f};

  const u16* Ab = gp.A + (size_t)b * gp.aBS;
  const u16* Bb = gp.B + (size_t)b * gp.bBS;

  const int scoff = (((l & 7) ^ (l >> 3)) << 3);

  const u16* aRow[4];
  const u16* bRow[4];
  u16* ldsA[4];
  u16* ldsB[4];
#pragma unroll
  for (int i = 0; i < 4; ++i) {
    const int r = w * 32 + i * 8 + (l >> 3);
    bRow[i] = Bb + (size_t)(n0 + r) * gp.Ktot + scoff;
    const int p = m0 + r;
    if (AMODE == 0) {
      const int pc = p < gp.Mrows ? p : gp.Mrows - 1;
      aRow[i] = Ab + (size_t)pc * gp.Ktot + scoff;
    } else {
      const int y = p >> gp.logW, x = p & ((1 << gp.logW) - 1);
      const int icoord = (y + gp.poff) * gp.wpad + (x + gp.poff);
      aRow[i] = Ab + (size_t)icoord * gp.cin + scoff;
    }
    ldsA[i] = smA + (w * 32 + i * 8) * 64;
    ldsB[i] = smB + (w * 32 + i * 8) * 64;
  }

  const int ktiles = gp.Ktot >> 6;
  int tap_off = 0, dx = 0, kc = 0;

  for (int kt = 0; kt < ktiles; ++kt) {
    int koffA;
    if (AMODE == 0)
      koffA = kt << 6;
    else
      koffA = tap_off * gp.cin + kc;
    const int koffB = kt << 6;
#pragma unroll
    for (int i = 0; i < 4; ++i) GLDS16(aRow[i] + koffA, ldsA[i]);
#pragma unroll
    for (int i = 0; i < 4; ++i) GLDS16(bRow[i] + koffB, ldsB[i]);

    if (AMODE == 1) {
      kc += 64;
      if (kc == gp.cin) {
        kc = 0;
        ++dx;
        ++tap_off;
        if (dx == 3) { dx = 0; tap_off += gp.wpad - 3; }
      }
    }

    __syncthreads();
#pragma unroll
    for (int ks = 0; ks < 2; ++ks) {
      bf16x8 av[4], bv[4];
      const int cc = (ks << 2) + (l >> 4);
#pragma unroll
      for (int mi = 0; mi < 4; ++mi) {
        const int row = wm * 64 + mi * 16 + (l & 15);
        av[mi] = *(const bf16x8*)((const char*)smA + (row << 7) +
                                  ((cc ^ (row & 7)) << 4));
      }
#pragma unroll
      for (int ni = 0; ni < 4; ++ni) {
        const int row = wn * 64 + ni * 16 + (l & 15);
        bv[ni] = *(const bf16x8*)((const char*)smB + (row << 7) +
                                  ((cc ^ (row & 7)) << 4));
      }
#pragma unroll
      for (int mi = 0; mi < 4; ++mi)
#pragma unroll
        for (int ni = 0; ni < 4; ++ni)
          acc[mi][ni] = __builtin_amdgcn_mfma_f32_16x16x32_bf16(
              av[mi], bv[ni], acc[mi][ni], 0, 0, 0);
    }
    __syncthreads();
  }

#pragma unroll
  for (int mi = 0; mi < 4; ++mi) {
#pragma unroll
    for (int ni = 0; ni < 4; ++ni) {
      const int ncol = n0 + wn * 64 + ni * 16 + (l & 15);
      const int mbase = m0 + wm * 64 + mi * 16 + ((l >> 4) << 2);
      const float bv_ =
          gp.bias ? gp.bias[(size_t)b * gp.biasBS + ncol] : 0.f;

      if constexpr (CW == 7) {
        u16* base = (u16*)gp.C;
        if (ncol < 256) {
#pragma unroll
          for (int r = 0; r < 4; ++r)
            base[(size_t)b * 1048576 + (size_t)(mbase + r) * 256 + ncol] =
                f2b(acc[mi][ni][r] + bv_);
        } else {
          u16x4 pk;
#pragma unroll
          for (int r = 0; r < 4; ++r) pk[r] = f2b(acc[mi][ni][r] + bv_);
          *(u16x4*)(base + 8388608 + (size_t)b * 1048576 +
                    (size_t)(ncol - 256) * 4096 + mbase) = pk;
        }
      } else {
#pragma unroll
        for (int reg = 0; reg < 4; ++reg) {
          const int mrow = mbase + reg;
          if (mrow >= gp.Mrows) continue;
          float v = acc[mi][ni][reg] * gp.scale + bv_;
          if (RELU) v = v > 0.f ? v : 0.f;
          if constexpr (CW == 0) {
            ((u16*)gp.C)[(size_t)b * gp.cBS + (size_t)mrow * gp.ldc + ncol] =
                f2b(v);
          } else if constexpr (CW == 5) {
            ((float*)gp.C)[(size_t)b * gp.cBS + (size_t)mrow * 256 + ncol] = v;
          }
        }
      }
    }
  }
}

// ---------------------------------------------------------------------------
// attnV split-K=4: SCORES[1025][4096] x V^T[256][4096], K-chunk 1024/block.
// grid (9, 2, 32): z = b*4 + sp. fp32 partials -> PAV[z][1025][256].
// ---------------------------------------------------------------------------
__global__ __launch_bounds__(256, 2) void k_attnv(const u16* __restrict__ S,
                                                  const u16* __restrict__ Vv,
                                                  float* __restrict__ PAV) {
  const int tid = threadIdx.x;
  const int l = tid & 63, w = tid >> 6;
  const int b = blockIdx.z >> 2, sp = blockIdx.z & 3;
  const int m0 = blockIdx.x * 128, n0 = blockIdx.y * 128;
  const int wm = w >> 1, wn = w & 1;

  __shared__ __align__(16) u16 smA[128 * 64];
  __shared__ __align__(16) u16 smB[128 * 64];

  f32x4 acc[4][4];
#pragma unroll
  for (int i = 0; i < 4; ++i)
#pragma unroll
    for (int j = 0; j < 4; ++j) acc[i][j] = (f32x4){0.f, 0.f, 0.f, 0.f};

  const u16* Ab = S + (size_t)b * 4198400 + sp * 1024;
  const u16* Bb = Vv + (size_t)b * 1048576 + sp * 1024;
  const int scoff = (((l & 7) ^ (l >> 3)) << 3);

  const u16* aRow[4];
  const u16* bRow[4];
  u16* ldsA[4];
  u16* ldsB[4];
#pragma unroll
  for (int i = 0; i < 4; ++i) {
    const int r = w * 32 + i * 8 + (l >> 3);
    bRow[i] = Bb + (size_t)(n0 + r) * 4096 + scoff;
    const int p = m0 + r;
    const int pc = p < 1025 ? p : 1024;
    aRow[i] = Ab + (size_t)pc * 4096 + scoff;
    ldsA[i] = smA + (w * 32 + i * 8) * 64;
    ldsB[i] = smB + (w * 32 + i * 8) * 64;
  }

  for (int kt = 0; kt < 16; ++kt) {
    const int koff = kt << 6;
#pragma unroll
    for (int i = 0; i < 4; ++i) GLDS16(aRow[i] + koff, ldsA[i]);
#pragma unroll
    for (int i = 0; i < 4; ++i) GLDS16(bRow[i] + koff, ldsB[i]);

    __syncthreads();
#pragma unroll
    for (int ks = 0; ks < 2; ++ks) {
      bf16x8 av[4], bv[4];
      const int cc = (ks << 2) + (l >> 4);
#pragma unroll
      for (int mi = 0; mi < 4; ++mi) {
        const int row = wm * 64 + mi * 16 + (l & 15);
        av[mi] = *(const bf16x8*)((const char*)smA + (row << 7) +
                                  ((cc ^ (row & 7)) << 4));
      }
#pragma unroll
      for (int ni = 0; ni < 4; ++ni) {
        const int row = wn * 64 + ni * 16 + (l & 15);
        bv[ni] = *(const bf16x8*)((const char*)smB + (row << 7) +
                                  ((cc ^ (row & 7)) << 4));
      }
#pragma unroll
      for (int mi = 0; mi < 4; ++mi)
#pragma unroll
        for (int ni = 0; ni < 4; ++ni)
          acc[mi][ni] = __builtin_amdgcn_mfma_f32_16x16x32_bf16(
              av[mi], bv[ni], acc[mi][ni], 0, 0, 0);
    }
    __syncthreads();
  }

  float* P = PAV + (size_t)blockIdx.z * 262400;
#pragma unroll
  for (int mi = 0; mi < 4; ++mi) {
#pragma unroll
    for (int ni = 0; ni < 4; ++ni) {
      const int ncol = n0 + wn * 64 + ni * 16 + (l & 15);
      const int mbase = m0 + wm * 64 + mi * 16 + ((l >> 4) << 2);
#pragma unroll
      for (int r = 0; r < 4; ++r) {
        const int mrow = mbase + r;
        if (mrow >= 1025) continue;
        P[(size_t)mrow * 256 + ncol] = acc[mi][ni][r];
      }
    }
  }
}

// reduce attnV partials: sum 4 splits; row0 -> out0 fp32; rows 1..1024 ->
// OCP 34x34-pad bf16. grid (257, 8).
__global__ __launch_bounds__(256) void k_reduceAttn(const float* __restrict__ PAV,
                                                    float* __restrict__ out0,
                                                    u16* __restrict__ OCP) {
  const int b = blockIdx.y;
  const int i4 = blockIdx.x * 256 + threadIdx.x;
  if (i4 >= 65600) return;  // 1025*256/4
  const int flat = i4 << 2;
  const int row = flat >> 8;
  const int col = flat & 255;
  const float* base = PAV + (size_t)(b * 4) * 262400 + (size_t)row * 256 + col;
  f32x4 s = *(const f32x4*)base;
  s += *(const f32x4*)(base + 262400);
  s += *(const f32x4*)(base + 524800);
  s += *(const f32x4*)(base + 787200);
  if (row == 0) {
    *(f32x4*)(out0 + (size_t)b * 256 + col) = s;
  } else {
    const int p = row - 1, y = p >> 5, x = p & 31;
    u16x4 r;
#pragma unroll
    for (int k = 0; k < 4; ++k) r[k] = f2b(s[k]);
    *(u16x4*)(OCP + ((size_t)b * 1156 + (size_t)(y + 1) * 34 + x + 1) * 256 +
              col) = r;
  }
}

// --------------------------- prep / misc kernels ---------------------------

__global__ __launch_bounds__(256) void k_prep_x(const float* __restrict__ x,
                                                u16* __restrict__ o) {
  __shared__ float t[32][65];
  const int b = blockIdx.z, c0 = blockIdx.y << 5, y = blockIdx.x;
  const float* src = x + ((size_t)b * 1280 + c0) * 4096 + (size_t)y * 64;
#pragma unroll
  for (int i = 0; i < 8; ++i) {
    const int idx = threadIdx.x + (i << 8);
    const int c = idx >> 6, xx = idx & 63;
    t[c][xx] = src[(size_t)c * 4096 + xx];
  }
  __syncthreads();
  u16* dst = o + ((size_t)b * 4356 + (size_t)(y + 1) * 66 + 1) * 1280 + c0;
  const int xx = threadIdx.x >> 2;
  const int cq = (threadIdx.x & 3) << 3;
  short8 pk;
#pragma unroll
  for (int j = 0; j < 8; ++j) pk[j] = (short)f2b(t[cq + j][xx]);
  *(short8*)(dst + (size_t)xx * 1280 + cq) = pk;
}

__device__ __forceinline__ void zb1(u16* p, int P, int C, int idx) {
  const int per_img = (4 * P - 4) * C;
  const int b = idx / per_img;
  const int r = idx % per_img;
  const int pix = r / C, c = r % C;
  int y, x;
  const int Pm = P - 1;
  if (pix < P) { y = 0; x = pix; }
  else if (pix < 2 * P) { y = Pm; x = pix - P; }
  else if (pix < 3 * P - 2) { y = pix - 2 * P + 1; x = 0; }
  else { y = pix - (3 * P - 2) + 1; x = Pm; }
  p[((size_t)b * P * P + (size_t)y * P + x) * C + c] = 0;
}

__global__ __launch_bounds__(256) void k_zero_borders(u16* XPAD, u16* H1,
                                                      u16* G2, u16* OCP) {
  const int nx = 8 * 260 * 1280;
  const int nh = 8 * 260 * 256;
  const int no = 8 * 132 * 256;
  const int total = nx + 2 * nh + no;
  for (int i = blockIdx.x * 256 + threadIdx.x; i < total;
       i += gridDim.x * 256) {
    if (i < nx) zb1(XPAD, 66, 1280, i);
    else if (i < nx + nh) zb1(H1, 66, 256, i - nx);
    else if (i < nx + 2 * nh) zb1(G2, 66, 256, i - nx - nh);
    else zb1(OCP, 34, 256, i - nx - 2 * nh);
  }
}

__global__ __launch_bounds__(256) void k_prep_all(
    const float* __restrict__ w1, const float* __restrict__ w2,
    const float* __restrict__ wsc, const float* __restrict__ wd0,
    const float* __restrict__ wd1, const float* __restrict__ b2,
    const float* __restrict__ bsc, const float* __restrict__ q,
    u16* __restrict__ W1R, u16* __restrict__ WCAT2, u16* __restrict__ WD0R,
    u16* __restrict__ WD1R, float* __restrict__ BB2, u16* __restrict__ QB) {
  const int N1 = 2949120, N2 = 917504, N3 = 589824, N4 = 589824,
            N5 = 2099200, N6 = 256;
  const int T = N1 + N2 + N3 + N4 + N5 + N6;
  for (int i = blockIdx.x * 256 + threadIdx.x; i < T; i += gridDim.x * 256) {
    if (i < N1) {
      const int ci = i % 1280, r = i / 1280, t = r % 9, co = r / 9;
      W1R[i] = f2b(w1[((size_t)co * 1280 + ci) * 9 + t]);
    } else if (i < N1 + N2) {
      const int k = i - N1;
      const int co = k / 3584, kk = k % 3584;
      float v;
      if (kk < 2304) {
        const int tap = kk / 256, ci = kk % 256;
        v = w2[((size_t)co * 256 + ci) * 9 + tap];
      } else {
        v = wsc[(size_t)co * 1280 + (kk - 2304)];
      }
      WCAT2[k] = f2b(v);
    } else if (i < N1 + N2 + N3) {
      const int k = i - N1 - N2;
      const int ci = k % 256, r = k / 256, t = r % 9, co = r / 9;
      WD0R[k] = f2b(wd0[((size_t)co * 256 + ci) * 9 + t]);
    } else if (i < N1 + N2 + N3 + N4) {
      const int k = i - N1 - N2 - N3;
      const int ci = k % 256, r = k / 256, t = r % 9, co = r / 9;
      WD1R[k] = f2b(wd1[((size_t)co * 256 + ci) * 9 + t]);
    } else if (i < N1 + N2 + N3 + N4 + N5) {
      const int k = i - N1 - N2 - N3 - N4;
      QB[k] = f2b(q[k] * 0.0625f);
    } else {
      const int k = i - N1 - N2 - N3 - N4 - N5;
      BB2[k] = b2[k] + bsc[k];
    }
  }
}

__global__ __launch_bounds__(256) void k_foldkv(
    const float* __restrict__ wk, const float* __restrict__ wv,
    const float* __restrict__ bk, const float* __restrict__ bv,
    const float* __restrict__ g, const float* __restrict__ lnb,
    const float* __restrict__ st, u16* __restrict__ WKVB,
    float* __restrict__ BKVB) {
  const int idx = blockIdx.x * 256 + threadIdx.x;
  const int b = idx >> 9, j = idx & 511;
  const float mu = st[b * 2] * (1.f / 1048576.f);
  const float var = st[b * 2 + 1] * (1.f / 1048576.f) - mu * mu;
  const float rs = rsqrtf(var + 1e-6f);
  const float* wrow = (j < 256) ? wk + (size_t)j * 256 : wv + (size_t)(j - 256) * 256;
  float acc = (j < 256) ? bk[j] : bv[j - 256];
  u16* orow = WKVB + ((size_t)b * 512 + j) * 256;
  for (int c = 0; c < 256; ++c) {
    const float wv_ = wrow[c];
    orow[c] = f2b(wv_ * g[c] * rs);
    acc += wv_ * (lnb[c] - mu * rs * g[c]);
  }
  BKVB[b * 512 + j] = acc;
}

template <bool PAD>
__global__ __launch_bounds__(256) void k_gn_norm(const float* __restrict__ x,
                                                 const float* __restrict__ st,
                                                 const float* __restrict__ g,
                                                 const float* __restrict__ bb,
                                                 u16* __restrict__ o) {
  const int b = blockIdx.y;
  const float mu = st[b * 2] * (1.f / 1048576.f);
  const float var = st[b * 2 + 1] * (1.f / 1048576.f) - mu * mu;
  const float rs = rsqrtf(var + 1e-6f);
  const int i4 = blockIdx.x * 256 + threadIdx.x;
  const f32x4 v = ((const f32x4*)(x + (size_t)b * 1048576))[i4];
  const int flat = i4 << 2;
  const int c = flat & 255;
  const int p = flat >> 8;
  const f32x4 gv = *(const f32x4*)(g + c);
  const f32x4 bv = *(const f32x4*)(bb + c);
  u16x4 r;
#pragma unroll
  for (int k = 0; k < 4; ++k) r[k] = f2b((v[k] - mu) * rs * gv[k] + bv[k]);
  size_t oidx;
  if (PAD) {
    const int y = p >> 6, xx = p & 63;
    oidx = ((size_t)b * 4356 + (size_t)(y + 1) * 66 + xx + 1) * 256 + c;
  } else {
    oidx = ((size_t)b * 4096 + p) * 256 + c;
  }
  *(u16x4*)(o + oidx) = r;
}

__global__ __launch_bounds__(256) void k_softmax(u16* __restrict__ s) {
  const size_t row = blockIdx.x;
  u16* p = s + row * 4096;
  const int t = threadIdx.x;
  const short8 r0 = ((const short8*)p)[t];
  const short8 r1 = ((const short8*)p)[t + 256];
  float v[16];
#pragma unroll
  for (int i = 0; i < 8; ++i) {
    v[i] = b2f((u16)r0[i]);
    v[8 + i] = b2f((u16)r1[i]);
  }
  float m = v[0];
#pragma unroll
  for (int i = 1; i < 16; ++i) m = fmaxf(m, v[i]);
#pragma unroll
  for (int o = 32; o; o >>= 1) m = fmaxf(m, __shfl_xor(m, o));
  __shared__ float lm[4], lsum[4];
  const int w = t >> 6;
  if ((t & 63) == 0) lm[w] = m;
  __syncthreads();
  m = fmaxf(fmaxf(lm[0], lm[1]), fmaxf(lm[2], lm[3]));
  float sum = 0.f;
#pragma unroll
  for (int i = 0; i < 16; ++i) {
    v[i] = __expf(v[i] - m);
    sum += v[i];
  }
#pragma unroll
  for (int o = 32; o; o >>= 1) sum += __shfl_xor(sum, o);
  if ((t & 63) == 0) lsum[w] = sum;
  __syncthreads();
  sum = lsum[0] + lsum[1] + lsum[2] + lsum[3];
  const float inv = 1.f / sum;
  short8 o0, o1;
#pragma unroll
  for (int i = 0; i < 8; ++i) {
    o0[i] = (short)f2b(v[i] * inv);
    o1[i] = (short)f2b(v[8 + i] * inv);
  }
  ((short8*)p)[t] = o0;
  ((short8*)p)[t + 256] = o1;
}

// bilinear 32->64 + add F -> mid, fused gn2 stats. grid (64, 8).
__global__ __launch_bounds__(256) void k_resize_add(const float* __restrict__ d0,
                                                    const float* __restrict__ F,
                                                    float* __restrict__ mid,
                                                    float* __restrict__ st) {
  const int b = blockIdx.y;
  const float* db = d0 + (size_t)b * 262144;
  const float* Fb = F + (size_t)b * 1048576;
  float* mb = mid + (size_t)b * 1048576;
  float ls = 0.f, lq = 0.f;
  for (int i4 = blockIdx.x * 256 + threadIdx.x; i4 < 262144;
       i4 += 64 * 256) {
    const int flat = i4 << 2;
    const int c = flat & 255;
    const int p = flat >> 8;
    const int y = p >> 6, x = p & 63;
    const float fy = y * (31.f / 63.f);
    const int y0 = (int)fy;
    const float wy = fy - y0;
    const int y1 = y0 + 1 > 31 ? 31 : y0 + 1;
    const float fx = x * (31.f / 63.f);
    const int x0 = (int)fx;
    const float wx = fx - x0;
    const int x1 = x0 + 1 > 31 ? 31 : x0 + 1;
    const f32x4 a = *(const f32x4*)(db + ((size_t)(y0 * 32 + x0) << 8) + c);
    const f32x4 bq = *(const f32x4*)(db + ((size_t)(y0 * 32 + x1) << 8) + c);
    const f32x4 cq = *(const f32x4*)(db + ((size_t)(y1 * 32 + x0) << 8) + c);
    const f32x4 dq = *(const f32x4*)(db + ((size_t)(y1 * 32 + x1) << 8) + c);
    f32x4 r = (a * (1.f - wx) + bq * wx) * (1.f - wy) +
              (cq * (1.f - wx) + dq * wx) * wy;
    r += *(const f32x4*)(Fb + flat);
    *(f32x4*)(mb + flat) = r;
    ls += r[0] + r[1] + r[2] + r[3];
    lq += r[0] * r[0] + r[1] * r[1] + r[2] * r[2] + r[3] * r[3];
  }
#pragma unroll
  for (int o = 32; o; o >>= 1) {
    ls += __shfl_down(ls, o);
    lq += __shfl_down(lq, o);
  }
  __shared__ float red[8];
  const int w = threadIdx.x >> 6;
  if ((threadIdx.x & 63) == 0) { red[w * 2] = ls; red[w * 2 + 1] = lq; }
  __syncthreads();
  if (threadIdx.x == 0) {
    atomicAdd(&st[16 + b * 2], red[0] + red[2] + red[4] + red[6]);
    atomicAdd(&st[16 + b * 2 + 1], red[1] + red[3] + red[5] + red[7]);
  }
}

// ---------------------------------------------------------------------------

extern "C" void kernel_launch(void* const* d_in, const int* in_sizes, int n_in,
                              void* d_out, int out_size, void* d_ws,
                              size_t ws_size, hipStream_t stream) {
  (void)in_sizes; (void)n_in; (void)out_size;

  const float* q   = (const float*)d_in[0];
  const float* xdc = (const float*)d_in[1];
  const float* w1  = (const float*)d_in[2];
  const float* b1  = (const float*)d_in[3];
  const float* w2  = (const float*)d_in[4];
  const float* b2  = (const float*)d_in[5];
  const float* wsc = (const float*)d_in[6];
  const float* bsc = (const float*)d_in[7];
  const float* lng = (const float*)d_in[8];
  const float* lnb = (const float*)d_in[9];
  const float* wk  = (const float*)d_in[10];
  const float* bk  = (const float*)d_in[11];
  const float* wv  = (const float*)d_in[12];
  const float* bv  = (const float*)d_in[13];
  const float* wd0 = (const float*)d_in[14];
  const float* bd0 = (const float*)d_in[15];
  const float* wd1 = (const float*)d_in[16];
  const float* bd1 = (const float*)d_in[17];

  char* ws = (char*)d_ws;
  size_t cur = 0;
  auto alloc = [&](size_t sz) {
    char* p = ws + cur;
    cur += sz;
    return p;
  };
  u16* XPAD  = (u16*)alloc(89194496);   // 8*66*66*1280; SCORES alias later
  u16* W1R   = (u16*)alloc(5898240);
  u16* WCAT2 = (u16*)alloc(1835008);    // 256 x 3584 (w2 taps || wsc)
  u16* WD0R  = (u16*)alloc(1179648);
  u16* WD1R  = (u16*)alloc(1179648);
  u16* WKVB  = (u16*)alloc(2097152);    // 8 x 512 x 256 folded kv weights
  float* BKVB = (float*)alloc(16384);   // 8 x 512
  float* BB2 = (float*)alloc(1024);     // b2 + bsc
  u16* H1    = (u16*)alloc(17842176);   // conv1 out, padded NHWC bf16
  float* F   = (float*)alloc(33554432); // feat_diff NHWC fp32
  u16* FB    = (u16*)alloc(16777216);   // bf16(F), unnormalized
  u16* KT    = (u16*)alloc(16777216);   // key [pixel][256]
  u16* V     = (u16*)alloc(16777216);   // value [f][pixel] (MUST follow KT)
  u16* QB    = (u16*)alloc(4198400);    // query bf16 [1025][256], pre-scaled
  u16* OCP   = (u16*)alloc(4734976);    // attn spatial out, 34x34 pad NHWC
  float* D0O = (float*)alloc(8388608);  // dh0 out NHWC fp32 (32x32)
  float* MID = (float*)alloc(33554432); // out_p mid NHWC fp32
  u16* G2    = (u16*)alloc(17842176);   // gn2 out, padded NHWC bf16
  float* ST  = (float*)alloc(256);      // [0:16) gn1, [16:32) gn2
  u16* SCORES = XPAD;                   // XPAD dead after conv2 (seg2 read)
  u16* PART = (u16*)F;                  // 33.5MB bf16 conv1 partials over F
  float* PAV  = D0O;                    // 33.6MB attnV partials over D0O+MID
  (void)V;

  if (ws_size < cur) return;

  float* out0 = (float*)d_out;
  float* out1 = (float*)d_out + 2048;

  hipMemsetAsync(ST, 0, 256, stream);
  k_zero_borders<<<2048, 256, 0, stream>>>(XPAD, H1, G2, OCP);
  k_prep_x<<<dim3(64, 40, 8), 256, 0, stream>>>(xdc, XPAD);
  k_prep_all<<<4096, 256, 0, stream>>>(w1, w2, wsc, wd0, wd1, b2, bsc, q, W1R,
                                       WCAT2, WD0R, WD1R, BB2, QB);

  // conv1 3x3 via reg-prefetch 256x256 split-K kernel -> bf16 partials -> H1
  {
    G256 g{};
    g.A = XPAD; g.B = W1R; g.P = PART;
    g.aBS = 5575680; g.Ktot = 11520;
    g.cin = 1280; g.logW = 6; g.wpad = 66; g.poff = 0;
    k_gemm256<<<256, 512, 0, stream>>>(g);
    k_reduceH1<<<8192, 256, 0, stream>>>(PART, b1, H1);
  }
  // conv2 3x3 (K=2304 over H1) + fused shortcut (K=1280 over XPAD center):
  {
    GP g{};
    g.A = H1; g.B = WCAT2; g.bias = BB2; g.aux = XPAD; g.C = F;
    g.out0 = (float*)FB; g.st = ST;
    g.aBS = 1115136; g.bBS = 0; g.cBS = 1048576; g.auxBS = 5575680;
    g.Ktot = 3584; g.Mrows = 4096; g.ldc = 256;
    g.cin = 256; g.logW = 6; g.wpad = 66; g.poff = 0; g.scale = 1.f;
    k_gemm8<2, 8><<<dim3(32, 1, 8), 512, 0, stream>>>(g);
  }
  // fold gn1 into kv weights (per batch)
  k_foldkv<<<16, 256, 0, stream>>>(wk, wv, bk, bv, lng, lnb, ST, WKVB, BKVB);
  // fused key+value 1x1: FB x WKVB(+BKVB) -> KT, V
  {
    GP g{};
    g.A = FB; g.B = WKVB; g.bias = BKVB; g.C = KT;
    g.aBS = 1048576; g.bBS = 131072; g.cBS = 0; g.biasBS = 512;
    g.Ktot = 256; g.Mrows = 4096; g.ldc = 256; g.scale = 1.f;
    k_gemm<0, 7, false><<<dim3(32, 4, 8), 256, 0, stream>>>(g);
  }
  // scores: QB (pre-scaled) x KT^T -> SCORES bf16 [1025][4096]
  {
    GP g{};
    g.A = QB; g.B = KT; g.bias = nullptr; g.C = SCORES;
    g.aBS = 262400; g.bBS = 1048576; g.cBS = 4198400;
    g.Ktot = 256; g.Mrows = 1025; g.ldc = 4096; g.scale = 1.f;
    k_gemm<0, 0, false><<<dim3(9, 32, 8), 256, 0, stream>>>(g);
  }
  k_softmax<<<8200, 256, 0, stream>>>(SCORES);
  // attn out: split-K=4 -> partials -> reduce (out0 + OCP)
  k_attnv<<<dim3(9, 2, 32), 256, 0, stream>>>(SCORES, V, PAV);
  k_reduceAttn<<<dim3(257, 8), 256, 0, stream>>>(PAV, out0, OCP);
  // dh0 3x3 @32x32 (overwrites dead PAV region at D0O)
  {
    GP g{};
    g.A = OCP; g.B = WD0R; g.bias = bd0; g.C = D0O;
    g.aBS = 295936; g.bBS = 0; g.cBS = 262144; g.biasBS = 0;
    g.Ktot = 2304; g.Mrows = 1024; g.ldc = 256;
    g.cin = 256; g.logW = 5; g.wpad = 34; g.poff = 0; g.scale = 1.f;
    k_gemm<1, 5, true><<<dim3(8, 2, 8), 256, 0, stream>>>(g);
  }
  // bilinear upsample + add F -> MID, + gn2 stats (1024 atomics total)
  k_resize_add<<<dim3(64, 8), 256, 0, stream>>>(D0O, F, MID, ST);
  k_gn_norm<true><<<dim3(1024, 8), 256, 0, stream>>>(MID, ST + 16, lng, lnb, G2);
  // dh1 3x3: G2 x WD1R, relu(acc+bias)+MID -> out1 (NCHW fp32)
  {
    GP g{};
    g.A = G2; g.B = WD1R; g.bias = bd1; g.C = out1; g.aux = MID;
    g.aBS = 1115136; g.bBS = 0; g.cBS = 1048576; g.auxBS = 1048576;
    g.Ktot = 2304; g.Mrows = 4096; g.ldc = 256;
    g.cin = 256; g.logW = 6; g.wpad = 66; g.poff = 0; g.scale = 1.f;
    k_gemm8<1, 6><<<dim3(32, 1, 8), 512, 0, stream>>>(g);
  }
}